// Round 13
// baseline (394.738 us; speedup 1.0000x reference)
//
#include <hip/hip_runtime.h>

#define NR 32768   // rows (b*w*h)
#define CD 256     // emb dim
#define KD 8192    // dict size

typedef __attribute__((ext_vector_type(8))) _Float16 f16x8;
typedef __attribute__((ext_vector_type(4))) _Float16 f16x4;
typedef __attribute__((ext_vector_type(4))) float f32x4;

// ---- workspace float offsets ----
#define F_XH      0ull          // f16[32768][256] hi  (16MB)
#define F_XL      4194304ull    // f16[32768][256] lo  (16MB)
#define F_EH      8388608ull    // f16[8192][256] hi   (4MB)
#define F_EMBT    9437184ull    // fp32 embedT[256][8192] (8MB, rescore; tail-read pad)
#define F_E2N     11534336ull   // 8192  (-0.5*e2, fast path)
#define F_E2NP    11542528ull   // 8192  (numpy-emulated e2)
#define F_IDS     11550720ull   // 32768 ints
#define F_FLAGCNT 11583488ull
#define F_LOSS    11583489ull
#define F_FLAGLST 11583490ull   // up to 32768 ints
#define F_COUNTS  11616258ull   // 8192 ints
#define F_CURSOR  11624450ull   // 8192 ints
#define F_OFFS    11632642ull   // 8192 ints
#define F_BUCKET  11640834ull   // 32768 ints
#define F_PBD     11673602ull   // 2048*8 floats
#define F_PBI     11689986ull   // 2048*8 ints

// ---- output float offsets ----
#define OUT_ST   0ull
#define OUT_LOSS 8388608ull
#define OUT_IDS  8388609ull
#define OUT_NEMB 8421377ull
#define OUT_NUM  10518529ull
#define OUT_ENC  10526721ull

// numpy pairwise_sum for a 128-block: 8 accumulators, fixed combine tree.
__device__ __forceinline__ float np_pw128(const float* p) {
    float r0 = p[0], r1 = p[1], r2 = p[2], r3 = p[3];
    float r4 = p[4], r5 = p[5], r6 = p[6], r7 = p[7];
    for (int i = 8; i < 128; i += 8) {
        r0 += p[i + 0]; r1 += p[i + 1]; r2 += p[i + 2]; r3 += p[i + 3];
        r4 += p[i + 4]; r5 += p[i + 5]; r6 += p[i + 6]; r7 += p[i + 7];
    }
    return ((r0 + r1) + (r2 + r3)) + ((r4 + r5) + (r6 + r7));
}

// x (b,c,h,w) -> xh/xl[n][c] f16 split, n = b*1024 + w*32 + h
__global__ void k_cvt_x(const float* __restrict__ x,
                        _Float16* __restrict__ xh, _Float16* __restrict__ xl) {
    __shared__ float t[32 * 529];   // [c32][h16*33 + w]
    const int bx = blockIdx.x;
    const int b = bx >> 4, cg = (bx >> 1) & 7, h0 = (bx & 1) * 16;
    const int tid = threadIdx.x;
    const float* src = x + ((size_t)(b * 256 + cg * 32)) * 1024 + h0 * 32;
    #pragma unroll 4
    for (int i = 0; i < 16; ++i) {
        const int e4 = i * 256 + tid;          // quad index
        const int c = e4 >> 7, rem = e4 & 127;
        const int hh = rem >> 3, w4 = (rem & 7) * 4;
        const float4 v = *(const float4*)(src + (size_t)c * 1024 + hh * 32 + w4);
        float* dst = &t[c * 529 + hh * 33 + w4];
        dst[0] = v.x; dst[1] = v.y; dst[2] = v.z; dst[3] = v.w;
    }
    __syncthreads();
    const int nj = tid >> 3;              // 32 rows per iter
    const int c4 = (tid & 7) * 4;         // 4 consecutive c per lane
    #pragma unroll 4
    for (int i = 0; i < 16; ++i) {
        const int ns = i * 32 + nj;       // 0..511 = w*16 + hh
        const int w = ns >> 4, hh = ns & 15;
        f16x4 hv, lv;
        #pragma unroll
        for (int j = 0; j < 4; ++j) {
            const float v = t[(c4 + j) * 529 + hh * 33 + w];
            const _Float16 hi = (_Float16)v;
            hv[j] = hi;
            lv[j] = (_Float16)(v - (float)hi);
        }
        const size_t o = ((size_t)(b * 1024 + w * 32 + h0 + hh)) * 256 + cg * 32 + c4;
        *(f16x4*)&xh[o] = hv;
        *(f16x4*)&xl[o] = lv;
    }
}

// fused embed prep: eh f16 + e2n = -0.5*|e|^2 + numpy-emulated e2np.
__global__ void k_prep_e2(const float* __restrict__ embed, _Float16* __restrict__ eh,
                          float* __restrict__ e2n, float* __restrict__ e2np) {
    const int lane = threadIdx.x & 63;
    const int wv = threadIdx.x >> 6;
    #pragma unroll
    for (int i = 0; i < 8; ++i) {
        const int k = blockIdx.x * 32 + wv * 8 + i;
        const float4 v = *(const float4*)(embed + (size_t)k * CD + lane * 4);
        f16x4 h;
        h[0] = (_Float16)v.x; h[1] = (_Float16)v.y;
        h[2] = (_Float16)v.z; h[3] = (_Float16)v.w;
        *(f16x4*)&eh[(size_t)k * CD + lane * 4] = h;
        float s = v.x * v.x + v.y * v.y + v.z * v.z + v.w * v.w;
        #pragma unroll
        for (int off = 1; off < 64; off <<= 1) s += __shfl_xor(s, off);
        if (lane == 0) e2n[k] = -0.5f * s;
    }
    const int k = blockIdx.x * 32 + wv * 8 + (lane >> 3);
    const int j = lane & 7;
    float hsum[2];
    #pragma unroll
    for (int half = 0; half < 2; ++half) {
        float r = 0.f;
        for (int i = 0; i < 16; ++i) {
            float v = embed[(size_t)k * CD + half * 128 + j + i * 8];
            float sq = v * v;
            asm volatile("" : "+v"(sq));   // round v*v to fp32 (block contraction)
            r += sq;
        }
        float s = r + __shfl_xor(r, 1);
        s = s + __shfl_xor(s, 2);
        s = s + __shfl_xor(s, 4);
        hsum[half] = s;
    }
    if (j == 0) e2np[k] = hsum[0] + hsum[1];
}

// embed (k,c) -> embedT[c][k] fp32 (rescore only)
__global__ void k_epose(const float* __restrict__ embed, float* __restrict__ embedT) {
    int kt = blockIdx.x >> 2, ct = blockIdx.x & 3;
    __shared__ float t[64][65];
    int tid = threadIdx.x;
    #pragma unroll
    for (int i = 0; i < 16; ++i) {
        int e = tid + i * 256; int r = e >> 6, c = e & 63;
        t[r][c] = embed[(size_t)(kt * 64 + r) * CD + ct * 64 + c];
    }
    __syncthreads();
    #pragma unroll
    for (int i = 0; i < 16; ++i) {
        int e = tid + i * 256; int c = e >> 6, r = e & 63;
        embedT[(size_t)(ct * 64 + c) * KD + kt * 64 + r] = t[r][c];
    }
}

// ============================================================================
// Operand-swapped MFMA argmin — R7 pipeline at HALF size for 2 blocks/CU.
// Block: 256 thr (4 code-waves), 64 rows resident (32KB at LDSB=0),
// A (eh) ring-3 x 16KB (256 codes x 32 c chunk; 4 loads/thread/stage) at
// [32768,81920). LDS total 81920 B = 160KB/2 -> 2 blocks/CU. Grid 512.
// Per step s: stage s+2 (buf (s+2)%3), compute s (buf s%3), vmcnt(4) +
// raw s_barrier (leaves newest stage's 4 loads in flight). Tail stages
// (s>=256) use the same formula reading past eh into embedT (allocated),
// landing in dead ring bufs. Merge scratch reuses buf0 (dead at epilogue).
// MFMA C-init carries the -0.5*e2 bias.
// ============================================================================
#define LDSB 0
#define LDSA 32768
#define LDSM 32768   // merge scratch overlaps A-buf0 (dead at epilogue)
__global__ __launch_bounds__(256, 2) void k_mfma(
    const _Float16* __restrict__ xh, const _Float16* __restrict__ eh,
    const float* __restrict__ e2n, int* __restrict__ ids,
    int* __restrict__ flag_cnt, int* __restrict__ flag_list,
    int* __restrict__ counts)
{
    __shared__ __attribute__((aligned(16))) char smem[81920];
    const int tid = threadIdx.x;
    const int wm = tid >> 6, l = tid & 63;     // 4 code-waves
    const int lr = l & 15, q = l >> 4;
    const int n0 = blockIdx.x * 64;

    // ---- stage B (xh, 64 rows) resident, swizzled slot' = slot ^ (row&15) ----
    #pragma unroll
    for (int i = 0; i < 8; ++i) {
        const int row = i * 8 + (tid >> 5);
        const int slot = tid & 31;
        const _Float16* src = xh + (size_t)(n0 + row) * 256 + ((slot ^ (row & 15)) * 8);
        __builtin_amdgcn_global_load_lds(
            (const __attribute__((address_space(1))) unsigned int*)src,
            (__attribute__((address_space(3))) unsigned int*)(smem + LDSB + row * 512 + slot * 16),
            16, 0, 0);
    }

    // ---- A stage: step s covers codes [(s>>3)*256,+256) x c [(s&7)*32,+32).
    // 4 x 16B loads/thread. s>=256 reads into embedT region (allocated pad).
    auto STAGE_A = [&](int s) {
        const int bufo = LDSA + (s % 3) * 16384;
        #pragma unroll
        for (int i = 0; i < 4; ++i) {
            const int code = i * 64 + (tid >> 2);
            const int slot = tid & 3;
            const _Float16* src = eh + (size_t)((s >> 3) * 256 + code) * 256
                                     + (s & 7) * 32 + ((slot ^ ((code >> 1) & 3)) * 8);
            __builtin_amdgcn_global_load_lds(
                (const __attribute__((address_space(1))) unsigned int*)src,
                (__attribute__((address_space(3))) unsigned int*)
                    (smem + bufo + code * 64 + slot * 16),
                16, 0, 0);
        }
    };

    // ---- prologue: e2 bias window 0; stage steps 0,1; wait B+step0 ----
    f32x4 e2c[4];
    #pragma unroll
    for (int m = 0; m < 4; ++m)
        e2c[m] = *(const f32x4*)(e2n + wm * 64 + m * 16 + q * 4);
    STAGE_A(0); STAGE_A(1);
    __builtin_amdgcn_sched_barrier(0);
    asm volatile("s_waitcnt vmcnt(4)" ::: "memory");
    __builtin_amdgcn_s_barrier();
    __builtin_amdgcn_sched_barrier(0);

    f32x4 acc[4][4];
    float m1[4], m2[4]; int i1[4];
    #pragma unroll
    for (int n = 0; n < 4; ++n) { m1[n] = -3.4e38f; m2[n] = -3.4e38f; i1[n] = 0; }

    // precomputed LDS offsets
    int faoff[4];
    #pragma unroll
    for (int m = 0; m < 4; ++m) {
        const int code = wm * 64 + m * 16 + lr;
        faoff[m] = code * 64 + ((q ^ ((code >> 1) & 3)) * 16);
    }
    int fboff[4], rx[4];
    #pragma unroll
    for (int n = 0; n < 4; ++n) {
        const int row = n * 16 + lr;
        fboff[n] = LDSB + row * 512;
        rx[n] = row & 15;
    }

    #pragma unroll 1
    for (int cg = 0; cg < 32; ++cg) {
        #pragma unroll
        for (int cc = 0; cc < 8; ++cc) {
            const int s = cg * 8 + cc;
            if (cc == 6 && cg < 31) {   // prefetch next window's e2 bias
                #pragma unroll
                for (int m = 0; m < 4; ++m)
                    e2c[m] = *(const f32x4*)(e2n + (cg + 1) * 256 + wm * 64 + m * 16 + q * 4);
            }
            STAGE_A(s + 2);
            const int bufo = LDSA + (s % 3) * 16384;
            f16x8 fa[4], fb[4];
            #pragma unroll
            for (int m = 0; m < 4; ++m)
                fa[m] = *(const f16x8*)(smem + bufo + faoff[m]);
            #pragma unroll
            for (int n = 0; n < 4; ++n) {
                const int g = cc * 4 + q;
                fb[n] = *(const f16x8*)(smem + fboff[n] + ((g ^ rx[n]) * 16));
            }
            if (cc == 0) {
                #pragma unroll
                for (int m = 0; m < 4; ++m)
                    #pragma unroll
                    for (int n = 0; n < 4; ++n)
                        acc[m][n] = __builtin_amdgcn_mfma_f32_16x16x32_f16(fa[m], fb[n], e2c[m], 0, 0, 0);
            } else {
                #pragma unroll
                for (int m = 0; m < 4; ++m)
                    #pragma unroll
                    for (int n = 0; n < 4; ++n)
                        acc[m][n] = __builtin_amdgcn_mfma_f32_16x16x32_f16(fa[m], fb[n], acc[m][n], 0, 0, 0);
            }
            if (cc == 7) {   // fold window into per-lane top-2
                const int kb = cg * 256 + wm * 64 + q * 4;
                #pragma unroll
                for (int n = 0; n < 4; ++n)
                    #pragma unroll
                    for (int m = 0; m < 4; ++m)
                        #pragma unroll
                        for (int r = 0; r < 4; ++r) {
                            const float v = acc[m][n][r];
                            const bool g = v > m1[n];
                            m2[n] = fmaxf(m2[n], fminf(v, m1[n]));
                            m1[n] = fmaxf(m1[n], v);
                            i1[n] = g ? (kb + m * 16 + r) : i1[n];
                        }
            }
            __builtin_amdgcn_sched_barrier(0);
            asm volatile("s_waitcnt vmcnt(4)" ::: "memory");
            __builtin_amdgcn_s_barrier();
            __builtin_amdgcn_sched_barrier(0);
        }
    }

    // ---- cross-lane merge: lanes l, l+16, l+32, l+48 hold same rows ----
    #pragma unroll
    for (int off = 16; off < 64; off <<= 1) {
        #pragma unroll
        for (int n = 0; n < 4; ++n) {
            const float om1 = __shfl_xor(m1[n], off);
            const float om2 = __shfl_xor(m2[n], off);
            const int   oi  = __shfl_xor(i1[n], off);
            const bool g = om1 > m1[n];
            m2[n] = fmaxf(fminf(m1[n], om1), fmaxf(m2[n], om2));
            m1[n] = fmaxf(m1[n], om1);
            i1[n] = g ? oi : i1[n];
        }
    }
    // ---- cross-wave merge over 4 code-waves via LDS (A-buf0 dead) ----
    float* sm1 = (float*)(smem + LDSM);
    float* sm2 = (float*)(smem + LDSM + 1024);
    int*   si1 = (int*)  (smem + LDSM + 2048);
    __syncthreads();    // full drain (tail stages went to bufs 1,2)
    if (q == 0) {
        #pragma unroll
        for (int n = 0; n < 4; ++n) {
            const int row = n * 16 + lr;
            sm1[wm * 64 + row] = m1[n];
            sm2[wm * 64 + row] = m2[n];
            si1[wm * 64 + row] = i1[n];
        }
    }
    __syncthreads();
    if (tid < 64) {
        float a1 = sm1[tid], a2 = sm2[tid]; int ai = si1[tid];
        #pragma unroll
        for (int wq = 1; wq < 4; ++wq) {
            const float b1 = sm1[wq * 64 + tid], b2 = sm2[wq * 64 + tid];
            const int bi = si1[wq * 64 + tid];
            const bool g = b1 > a1;
            a2 = fmaxf(fminf(a1, b1), fmaxf(a2, b2));
            a1 = fmaxf(a1, b1);
            ai = g ? bi : ai;
        }
        const int n = n0 + tid;
        ids[n] = ai;
        atomicAdd(&counts[ai], 1);
        if (a1 - a2 < 2.5e-3f) {
            int p = atomicAdd(flag_cnt, 1);
            flag_list[p] = n;
        }
    }
}

// batched numpy-fp32-path rescore: 16 rows/group x 8 k-slices per block.
#define RG 16
__global__ __launch_bounds__(256) void k_rescore(
    const float* __restrict__ x, const float* __restrict__ embedT,
    const float* __restrict__ e2np, const int* __restrict__ flag_cnt,
    const int* __restrict__ flag_list, float* __restrict__ pbd, int* __restrict__ pbi)
{
    __shared__ float rowl[RG][256];
    __shared__ float sq[RG][256];
    __shared__ float x2s[RG];
    __shared__ float bdA[256];
    __shared__ int   biA[256];
    const int tid = threadIdx.x;
    int cnt = *flag_cnt; if (cnt > 2048) cnt = 2048;
    const int ngroups = (cnt + RG - 1) / RG;
    const int kt = blockIdx.x & 7;
    for (int g = blockIdx.x >> 3; g < ngroups; g += 64) {
        #pragma unroll
        for (int i = 0; i < RG; ++i) {
            int f = g * RG + i;
            float v = 0.f;
            if (f < cnt) {
                int n = flag_list[f];
                int b = n >> 10, wq = (n >> 5) & 31, hq = n & 31;
                v = x[((size_t)(b * 256 + tid)) * 1024 + hq * 32 + wq];
            }
            rowl[i][tid] = v;
            sq[i][tid] = v * v;       // product rounds at LDS store
        }
        __syncthreads();
        if (tid < RG) x2s[tid] = np_pw128(sq[tid]) + np_pw128(sq[tid] + 128);
        __syncthreads();

        float acc[RG][4];
        #pragma unroll
        for (int r = 0; r < RG; ++r)
            #pragma unroll
            for (int e = 0; e < 4; ++e) acc[r][e] = 0.f;
        for (int c = 0; c < 256; ++c) {
            const f32x4 bv = *(const f32x4*)&embedT[(size_t)c * KD + kt * 1024 + tid * 4];
            #pragma unroll
            for (int r = 0; r < RG; ++r) {
                const float av = rowl[r][c];
                acc[r][0] = fmaf(av, bv[0], acc[r][0]);
                acc[r][1] = fmaf(av, bv[1], acc[r][1]);
                acc[r][2] = fmaf(av, bv[2], acc[r][2]);
                acc[r][3] = fmaf(av, bv[3], acc[r][3]);
            }
        }
        #pragma unroll
        for (int r = 0; r < RG; ++r) {
            float bd = 3.4e38f; int bi = 0x7fffffff;
            #pragma unroll
            for (int e = 0; e < 4; ++e) {
                const int k = kt * 1024 + tid * 4 + e;
                const float d2 = (x2s[r] - 2.0f * acc[r][e]) + e2np[k];
                if (d2 < bd || (d2 == bd && k < bi)) { bd = d2; bi = k; }
            }
            bdA[tid] = bd; biA[tid] = bi;
            __syncthreads();
            for (int off = 128; off > 0; off >>= 1) {
                if (tid < off) {
                    float od = bdA[tid + off]; int oi = biA[tid + off];
                    if (od < bdA[tid] || (od == bdA[tid] && oi < biA[tid])) {
                        bdA[tid] = od; biA[tid] = oi;
                    }
                }
                __syncthreads();
            }
            if (tid == 0) {
                int f = g * RG + r;
                if (f < cnt) { pbd[f * 8 + kt] = bdA[0]; pbi[f * 8 + kt] = biA[0]; }
            }
            __syncthreads();
        }
    }
}

// merge kt-slices; adjust ids + counts for changed rows
__global__ void k_flagmerge(const int* __restrict__ flag_cnt, const int* __restrict__ flag_list,
                            const float* __restrict__ pbd, const int* __restrict__ pbi,
                            int* __restrict__ ids, int* __restrict__ counts) {
    int cnt = *flag_cnt; if (cnt > 2048) cnt = 2048;
    int f = blockIdx.x * 256 + threadIdx.x;
    if (f >= cnt) return;
    float bd = pbd[f * 8]; int bi = pbi[f * 8];
    #pragma unroll
    for (int kt = 1; kt < 8; ++kt) {
        float d = pbd[f * 8 + kt]; int i = pbi[f * 8 + kt];
        if (d < bd || (d == bd && i < bi)) { bd = d; bi = i; }
    }
    const int n = flag_list[f];
    const int old = ids[n];
    if (bi != old) {
        ids[n] = bi;
        atomicAdd(&counts[old], -1);
        atomicAdd(&counts[bi], 1);
    }
}

// st_out (= vqs) + loss, coalesced + float4-vectorized via LDS transpose.
__global__ __launch_bounds__(256) void k_output(
    const float* __restrict__ x, const float* __restrict__ embed,
    const int* __restrict__ ids, float* __restrict__ st,
    float* __restrict__ loss_ws)
{
    const int b = blockIdx.x >> 5, h = blockIdx.x & 31;
    const int tid = threadIdx.x;
    __shared__ int sid[32];
    __shared__ float vq[256 * 33];
    if (tid < 32) sid[tid] = ids[b * 1024 + tid * 32 + h];
    __syncthreads();
    #pragma unroll 4
    for (int w = 0; w < 32; ++w) {
        vq[tid * 33 + w] = embed[(size_t)sid[w] * CD + tid];
    }
    __syncthreads();
    float lsum = 0.f;
    const int j4 = (tid & 7) * 4;
    const int c0 = tid >> 3;
    const size_t base0 = (((size_t)b * 256) * 32 + h) * 32;
    #pragma unroll
    for (int it = 0; it < 8; ++it) {
        const int c = it * 32 + c0;
        const size_t a = base0 + (size_t)c * 1024 + j4;
        const float4 xv = *(const float4*)(x + a);
        float4 vv;
        vv.x = vq[c * 33 + j4 + 0];
        vv.y = vq[c * 33 + j4 + 1];
        vv.z = vq[c * 33 + j4 + 2];
        vv.w = vq[c * 33 + j4 + 3];
        *(float4*)(st + a) = vv;
        const float d0 = vv.x - xv.x, d1 = vv.y - xv.y;
        const float d2 = vv.z - xv.z, d3 = vv.w - xv.w;
        lsum = fmaf(d0, d0, lsum); lsum = fmaf(d1, d1, lsum);
        lsum = fmaf(d2, d2, lsum); lsum = fmaf(d3, d3, lsum);
    }
    #pragma unroll
    for (int off = 1; off < 64; off <<= 1) lsum += __shfl_xor(lsum, off);
    if ((tid & 63) == 0) atomicAdd(loss_ws, lsum);
}

__global__ void k_scan(const int* __restrict__ counts, int* __restrict__ offs,
                       float* __restrict__ track_num) {
    __shared__ int ps[257];
    const int tid = threadIdx.x;
    int loc[32]; int s = 0;
    const int base = tid * 32;
    #pragma unroll
    for (int j = 0; j < 32; ++j) { loc[j] = s; s += counts[base + j]; }
    ps[tid + 1] = s;
    if (tid == 0) ps[0] = 0;
    __syncthreads();
    if (tid == 0) for (int i = 1; i <= 256; ++i) ps[i] += ps[i - 1];
    __syncthreads();
    const int pre = ps[tid];
    #pragma unroll
    for (int j = 0; j < 32; ++j) {
        offs[base + j] = pre + loc[j];
        track_num[base + j] = (float)counts[base + j];
    }
}

// bucket fill + ids_out (fused)
__global__ void k_fill(const int* __restrict__ ids, const int* __restrict__ offs,
                       int* __restrict__ cursor, int* __restrict__ bucket,
                       float* __restrict__ ids_out) {
    int n = blockIdx.x * 256 + threadIdx.x;
    int id = ids[n];
    int p = atomicAdd(&cursor[id], 1);
    bucket[offs[id] + p] = n;
    int b = n >> 10, w = (n >> 5) & 31, h = n & 31;
    ids_out[b * 1024 + h * 32 + w] = (float)id;
}

// track_enc + new_embed + loss_out (after k_output in stream)
__global__ void k_gather(const _Float16* __restrict__ xh, const _Float16* __restrict__ xl,
                         const int* __restrict__ offs, const int* __restrict__ counts,
                         const int* __restrict__ bucket, float* __restrict__ enc,
                         float* __restrict__ nemb, const float* __restrict__ loss_ws,
                         float* __restrict__ loss_out) {
    const int k = blockIdx.x, c = threadIdx.x;
    const int o = offs[k], cnt = counts[k];
    float s = 0.f;
    for (int i = 0; i < cnt; ++i) {
        int n = bucket[o + i];
        s += (float)xh[(size_t)n * CD + c] + (float)xl[(size_t)n * CD + c];
    }
    enc[(size_t)k * CD + c] = s;
    const float factor = 1.0f + (1e-5f * 8192.0f) / 32768.0f;
    nemb[(size_t)k * CD + c] = s * factor / ((float)cnt + 1e-5f);
    if (k == 0 && c == 0) loss_out[0] = loss_ws[0] * (1.0f / 8388608.0f);
}

extern "C" void kernel_launch(void* const* d_in, const int* in_sizes, int n_in,
                              void* d_out, int out_size, void* d_ws, size_t ws_size,
                              hipStream_t stream)
{
    const float* x     = (const float*)d_in[0];
    const float* embed = (const float*)d_in[1];
    float* out = (float*)d_out;
    float* ws  = (float*)d_ws;

    _Float16* xh = (_Float16*)(ws + F_XH);
    _Float16* xl = (_Float16*)(ws + F_XL);
    _Float16* eh = (_Float16*)(ws + F_EH);
    float* embedT    = ws + F_EMBT;
    float* e2n       = ws + F_E2N;
    float* e2np      = ws + F_E2NP;
    int*   ids       = (int*)(ws + F_IDS);
    int*   flag_cnt  = (int*)(ws + F_FLAGCNT);
    float* loss_ws   = ws + F_LOSS;
    int*   flag_list = (int*)(ws + F_FLAGLST);
    int*   counts    = (int*)(ws + F_COUNTS);
    int*   cursor    = (int*)(ws + F_CURSOR);
    int*   offs      = (int*)(ws + F_OFFS);
    int*   bucket    = (int*)(ws + F_BUCKET);
    float* pbd       = ws + F_PBD;
    int*   pbi       = (int*)(ws + F_PBI);

    hipMemsetAsync(ws + F_FLAGCNT, 0, 2 * sizeof(float), stream);          // flag_cnt + loss
    hipMemsetAsync(ws + F_COUNTS, 0, 2 * 8192 * sizeof(float), stream);    // counts + cursor

    k_cvt_x    <<<512,  256, 0, stream>>>(x, xh, xl);
    k_prep_e2  <<<256,  256, 0, stream>>>(embed, eh, e2n, e2np);
    k_epose    <<<512,  256, 0, stream>>>(embed, embedT);
    k_mfma     <<<512,  256, 0, stream>>>(xh, eh, e2n, ids, flag_cnt, flag_list, counts);
    k_rescore  <<<512,  256, 0, stream>>>(x, embedT, e2np, flag_cnt, flag_list, pbd, pbi);
    k_flagmerge<<<8,    256, 0, stream>>>(flag_cnt, flag_list, pbd, pbi, ids, counts);
    k_output   <<<1024, 256, 0, stream>>>(x, embed, ids, out + OUT_ST, loss_ws);
    k_scan     <<<1,    256, 0, stream>>>(counts, offs, out + OUT_NUM);
    k_fill     <<<128,  256, 0, stream>>>(ids, offs, cursor, bucket, out + OUT_IDS);
    k_gather   <<<8192, 256, 0, stream>>>(xh, xl, offs, counts, bucket, out + OUT_ENC,
                                          out + OUT_NEMB, loss_ws, out + OUT_LOSS);
}

// Round 15
// 390.095 us; speedup vs baseline: 1.0119x; 1.0119x over previous
//
#include <hip/hip_runtime.h>

#define NR 32768   // rows (b*w*h)
#define CD 256     // emb dim
#define KD 8192    // dict size

typedef __attribute__((ext_vector_type(8))) _Float16 f16x8;
typedef __attribute__((ext_vector_type(4))) _Float16 f16x4;
typedef __attribute__((ext_vector_type(4))) float f32x4;

// ---- workspace float offsets ----
#define F_XH      0ull          // f16[32768][256] hi  (16MB)
#define F_XL      4194304ull    // f16[32768][256] lo  (16MB)
#define F_EH      8388608ull    // f16[8192][256] hi   (4MB)
#define F_EMBT    9437184ull    // fp32 embedT[256][8192] (8MB, rescore; tail-read pad)
#define F_E2N     11534336ull   // 8192  (-0.5*e2, fast path)
#define F_E2NP    11542528ull   // 8192  (numpy-emulated e2)
#define F_IDS     11550720ull   // 32768 ints
#define F_FLAGCNT 11583488ull
#define F_LOSS    11583489ull
#define F_FLAGLST 11583490ull   // up to 32768 ints
#define F_COUNTS  11616258ull   // 8192 ints
#define F_CURSOR  11624450ull   // 8192 ints
#define F_OFFS    11632642ull   // 8192 ints
#define F_BUCKET  11640834ull   // 32768 ints
#define F_PBD     11673602ull   // 2048*8 floats
#define F_PBI     11689986ull   // 2048*8 ints

// ---- output float offsets ----
#define OUT_ST   0ull
#define OUT_LOSS 8388608ull
#define OUT_IDS  8388609ull
#define OUT_NEMB 8421377ull
#define OUT_NUM  10518529ull
#define OUT_ENC  10526721ull

// numpy pairwise_sum for a 128-block: 8 accumulators, fixed combine tree.
__device__ __forceinline__ float np_pw128(const float* p) {
    float r0 = p[0], r1 = p[1], r2 = p[2], r3 = p[3];
    float r4 = p[4], r5 = p[5], r6 = p[6], r7 = p[7];
    for (int i = 8; i < 128; i += 8) {
        r0 += p[i + 0]; r1 += p[i + 1]; r2 += p[i + 2]; r3 += p[i + 3];
        r4 += p[i + 4]; r5 += p[i + 5]; r6 += p[i + 6]; r7 += p[i + 7];
    }
    return ((r0 + r1) + (r2 + r3)) + ((r4 + r5) + (r6 + r7));
}

// x (b,c,h,w) -> xh/xl[n][c] f16 split, n = b*1024 + w*32 + h
__global__ void k_cvt_x(const float* __restrict__ x,
                        _Float16* __restrict__ xh, _Float16* __restrict__ xl) {
    __shared__ float t[32 * 529];   // [c32][h16*33 + w]
    const int bx = blockIdx.x;
    const int b = bx >> 4, cg = (bx >> 1) & 7, h0 = (bx & 1) * 16;
    const int tid = threadIdx.x;
    const float* src = x + ((size_t)(b * 256 + cg * 32)) * 1024 + h0 * 32;
    #pragma unroll 4
    for (int i = 0; i < 16; ++i) {
        const int e4 = i * 256 + tid;          // quad index
        const int c = e4 >> 7, rem = e4 & 127;
        const int hh = rem >> 3, w4 = (rem & 7) * 4;
        const float4 v = *(const float4*)(src + (size_t)c * 1024 + hh * 32 + w4);
        float* dst = &t[c * 529 + hh * 33 + w4];
        dst[0] = v.x; dst[1] = v.y; dst[2] = v.z; dst[3] = v.w;
    }
    __syncthreads();
    const int nj = tid >> 3;              // 32 rows per iter
    const int c4 = (tid & 7) * 4;         // 4 consecutive c per lane
    #pragma unroll 4
    for (int i = 0; i < 16; ++i) {
        const int ns = i * 32 + nj;       // 0..511 = w*16 + hh
        const int w = ns >> 4, hh = ns & 15;
        f16x4 hv, lv;
        #pragma unroll
        for (int j = 0; j < 4; ++j) {
            const float v = t[(c4 + j) * 529 + hh * 33 + w];
            const _Float16 hi = (_Float16)v;
            hv[j] = hi;
            lv[j] = (_Float16)(v - (float)hi);
        }
        const size_t o = ((size_t)(b * 1024 + w * 32 + h0 + hh)) * 256 + cg * 32 + c4;
        *(f16x4*)&xh[o] = hv;
        *(f16x4*)&xl[o] = lv;
    }
}

// fused embed prep: eh f16 + e2n = -0.5*|e|^2 + numpy-emulated e2np.
__global__ void k_prep_e2(const float* __restrict__ embed, _Float16* __restrict__ eh,
                          float* __restrict__ e2n, float* __restrict__ e2np) {
    const int lane = threadIdx.x & 63;
    const int wv = threadIdx.x >> 6;
    #pragma unroll
    for (int i = 0; i < 8; ++i) {
        const int k = blockIdx.x * 32 + wv * 8 + i;
        const float4 v = *(const float4*)(embed + (size_t)k * CD + lane * 4);
        f16x4 h;
        h[0] = (_Float16)v.x; h[1] = (_Float16)v.y;
        h[2] = (_Float16)v.z; h[3] = (_Float16)v.w;
        *(f16x4*)&eh[(size_t)k * CD + lane * 4] = h;
        float s = v.x * v.x + v.y * v.y + v.z * v.z + v.w * v.w;
        #pragma unroll
        for (int off = 1; off < 64; off <<= 1) s += __shfl_xor(s, off);
        if (lane == 0) e2n[k] = -0.5f * s;
    }
    const int k = blockIdx.x * 32 + wv * 8 + (lane >> 3);
    const int j = lane & 7;
    float hsum[2];
    #pragma unroll
    for (int half = 0; half < 2; ++half) {
        float r = 0.f;
        for (int i = 0; i < 16; ++i) {
            float v = embed[(size_t)k * CD + half * 128 + j + i * 8];
            float sq = v * v;
            asm volatile("" : "+v"(sq));   // round v*v to fp32 (block contraction)
            r += sq;
        }
        float s = r + __shfl_xor(r, 1);
        s = s + __shfl_xor(s, 2);
        s = s + __shfl_xor(s, 4);
        hsum[half] = s;
    }
    if (j == 0) e2np[k] = hsum[0] + hsum[1];
}

// embed (k,c) -> embedT[c][k] fp32 (rescore only)
__global__ void k_epose(const float* __restrict__ embed, float* __restrict__ embedT) {
    int kt = blockIdx.x >> 2, ct = blockIdx.x & 3;
    __shared__ float t[64][65];
    int tid = threadIdx.x;
    #pragma unroll
    for (int i = 0; i < 16; ++i) {
        int e = tid + i * 256; int r = e >> 6, c = e & 63;
        t[r][c] = embed[(size_t)(kt * 64 + r) * CD + ct * 64 + c];
    }
    __syncthreads();
    #pragma unroll
    for (int i = 0; i < 16; ++i) {
        int e = tid + i * 256; int c = e >> 6, r = e & 63;
        embedT[(size_t)(ct * 64 + c) * KD + kt * 64 + r] = t[r][c];
    }
}

// ============================================================================
// Operand-swapped MFMA argmin — WAVE-PRIVATE A staging, NO barrier in K-loop.
// R14 + the missing end-of-step sched_barrier(0): pins each step's stage
// AFTER the previous step's ds_reads (LLVM doesn't alias global_load_lds
// writes vs LDS reads and could hoist; HW order is safe once issue order is).
// B (xh, 128 rows) shared read-only at [0,65536) (one prologue barrier).
// A (eh): wave-private 64-code x 32-c chunks (4KB), triple-buffered per wave
// at [65536 + w*12288, +12288). LDS = 160KiB exactly. Per step: stage s+2,
// wait own vmcnt(8), read fa (own region) + fb (shared B), 16 MFMA.
// No inter-wave sync in the loop -> waves drift; scheduler fills stalls.
// ============================================================================
#define LDSB 0
#define LDSA 65536
#define LDSM 65536   // merge scratch reuses A region (dead after __syncthreads)
__global__ __launch_bounds__(512, 1) void k_mfma(
    const _Float16* __restrict__ xh, const _Float16* __restrict__ eh,
    const float* __restrict__ e2n, int* __restrict__ ids,
    int* __restrict__ flag_cnt, int* __restrict__ flag_list,
    int* __restrict__ counts)
{
    __shared__ __attribute__((aligned(16))) char smem[163840];
    const int tid = threadIdx.x;
    const int w = tid >> 6, l = tid & 63;
    const int wm = w & 3, wn = w >> 2;        // 4 code-waves x 2 row-waves
    const int lr = l & 15, q = l >> 4;
    const int n0 = blockIdx.x * 128;
    const int AW = LDSA + w * 12288;          // my wave's A region (3 x 4KB)

    // ---- stage B (xh rows) shared, swizzled slot' = slot ^ (row&15) ----
    #pragma unroll
    for (int i = 0; i < 8; ++i) {
        const int row = i * 16 + (tid >> 5);
        const int slot = tid & 31;
        const _Float16* src = xh + (size_t)(n0 + row) * 256 + ((slot ^ (row & 15)) * 8);
        __builtin_amdgcn_global_load_lds(
            (const __attribute__((address_space(1))) unsigned int*)src,
            (__attribute__((address_space(3))) unsigned int*)(smem + LDSB + row * 512 + slot * 16),
            16, 0, 0);
    }

    // ---- my wave's A stage: step s covers my codes [win*256+wm*64, +64)
    //      x c [(s&7)*32, +32). 4 x 16B loads/lane; LDS dst linear.
    auto STAGE_A = [&](int s, int bufo) {
        #pragma unroll
        for (int i = 0; i < 4; ++i) {
            const int code = i * 16 + (l >> 2);
            const int slot = l & 3;
            const _Float16* src = eh + (size_t)((s >> 3) * 256 + wm * 64 + code) * 256
                                     + (s & 7) * 32 + ((slot ^ ((code >> 1) & 3)) * 8);
            __builtin_amdgcn_global_load_lds(
                (const __attribute__((address_space(1))) unsigned int*)src,
                (__attribute__((address_space(3))) unsigned int*)
                    (smem + AW + bufo + i * 1024 + l * 16),
                16, 0, 0);
        }
    };

    // ---- prologue: e2 bias window 0; stage my steps 0,1; drain B; barrier ----
    f32x4 e2c[4];
    #pragma unroll
    for (int m = 0; m < 4; ++m)
        e2c[m] = *(const f32x4*)(e2n + wm * 64 + m * 16 + q * 4);
    STAGE_A(0, 0);
    STAGE_A(1, 4096);
    __builtin_amdgcn_sched_barrier(0);
    asm volatile("s_waitcnt vmcnt(8)" ::: "memory");   // drains my B loads (+e2c)
    __builtin_amdgcn_s_barrier();                      // all waves: B complete
    __builtin_amdgcn_sched_barrier(0);

    f32x4 acc[4][4];
    float m1[4], m2[4]; int i1[4];
    #pragma unroll
    for (int n = 0; n < 4; ++n) { m1[n] = -3.4e38f; m2[n] = -3.4e38f; i1[n] = 0; }

    // fa LDS byte offsets (within my region, relative to buf base)
    int faoff[4];
    #pragma unroll
    for (int m = 0; m < 4; ++m)
        faoff[m] = AW + m * 1024 + lr * 64 + ((q ^ ((lr >> 1) & 3)) * 16);
    int fboff[4], rx[4];
    #pragma unroll
    for (int n = 0; n < 4; ++n) {
        const int row = wn * 64 + n * 16 + lr;
        fboff[n] = LDSB + row * 512;
        rx[n] = row & 15;
    }

    int cbo = 0, sbo = 8192;   // buf of step s / step s+2 (cycle 0,4096,8192)
    #define ADVB(v) (v) = ((v) == 8192) ? 0 : (v) + 4096

    #pragma unroll 1
    for (int cg = 0; cg < 32; ++cg) {
        #pragma unroll
        for (int cc = 0; cc < 8; ++cc) {
            const int s = cg * 8 + cc;
            // fence: prior step's ds_reads must precede this step's stage
            __builtin_amdgcn_sched_barrier(0);
            if (cc == 6 && cg < 31) {   // prefetch next window's e2 bias
                #pragma unroll
                for (int m = 0; m < 4; ++m)
                    e2c[m] = *(const f32x4*)(e2n + (cg + 1) * 256 + wm * 64 + m * 16 + q * 4);
            }
            STAGE_A(s + 2, sbo);
            __builtin_amdgcn_sched_barrier(0);
            asm volatile("s_waitcnt vmcnt(8)" ::: "memory");   // stage s landed
            __builtin_amdgcn_sched_barrier(0);
            f16x8 fa[4], fb[4];
            #pragma unroll
            for (int m = 0; m < 4; ++m)
                fa[m] = *(const f16x8*)(smem + cbo + faoff[m]);
            #pragma unroll
            for (int n = 0; n < 4; ++n) {
                const int g = cc * 4 + q;
                fb[n] = *(const f16x8*)(smem + fboff[n] + ((g ^ rx[n]) * 16));
            }
            if (cc == 0) {
                #pragma unroll
                for (int m = 0; m < 4; ++m)
                    #pragma unroll
                    for (int n = 0; n < 4; ++n)
                        acc[m][n] = __builtin_amdgcn_mfma_f32_16x16x32_f16(fa[m], fb[n], e2c[m], 0, 0, 0);
            } else {
                #pragma unroll
                for (int m = 0; m < 4; ++m)
                    #pragma unroll
                    for (int n = 0; n < 4; ++n)
                        acc[m][n] = __builtin_amdgcn_mfma_f32_16x16x32_f16(fa[m], fb[n], acc[m][n], 0, 0, 0);
            }
            if (cc == 7) {   // fold window into per-lane top-2
                const int kb = cg * 256 + wm * 64 + q * 4;
                #pragma unroll
                for (int n = 0; n < 4; ++n)
                    #pragma unroll
                    for (int m = 0; m < 4; ++m)
                        #pragma unroll
                        for (int r = 0; r < 4; ++r) {
                            const float v = acc[m][n][r];
                            const bool g = v > m1[n];
                            m2[n] = fmaxf(m2[n], fminf(v, m1[n]));
                            m1[n] = fmaxf(m1[n], v);
                            i1[n] = g ? (kb + m * 16 + r) : i1[n];
                        }
            }
            ADVB(cbo); ADVB(sbo);
        }
    }
    #undef ADVB

    // ---- cross-lane merge: lanes l, l+16, l+32, l+48 hold same row, diff codes
    #pragma unroll
    for (int off = 16; off < 64; off <<= 1) {
        #pragma unroll
        for (int n = 0; n < 4; ++n) {
            const float om1 = __shfl_xor(m1[n], off);
            const float om2 = __shfl_xor(m2[n], off);
            const int   oi  = __shfl_xor(i1[n], off);
            const bool g = om1 > m1[n];
            m2[n] = fmaxf(fminf(m1[n], om1), fmaxf(m2[n], om2));
            m1[n] = fmaxf(m1[n], om1);
            i1[n] = g ? oi : i1[n];
        }
    }
    // ---- cross-wave merge over wm (4 code-wave groups) via LDS (A dead) ----
    float* sm1 = (float*)(smem + LDSM);
    float* sm2 = (float*)(smem + LDSM + 2048);
    int*   si1 = (int*)  (smem + LDSM + 4096);
    __syncthreads();    // full drain (vmcnt 0 + barrier) incl. tail stages
    if (q == 0) {
        #pragma unroll
        for (int n = 0; n < 4; ++n) {
            const int row = wn * 64 + n * 16 + lr;
            sm1[wm * 128 + row] = m1[n];
            sm2[wm * 128 + row] = m2[n];
            si1[wm * 128 + row] = i1[n];
        }
    }
    __syncthreads();
    if (tid < 128) {
        float a1 = sm1[tid], a2 = sm2[tid]; int ai = si1[tid];
        #pragma unroll
        for (int wq = 1; wq < 4; ++wq) {
            const float b1 = sm1[wq * 128 + tid], b2 = sm2[wq * 128 + tid];
            const int bi = si1[wq * 128 + tid];
            const bool g = b1 > a1;
            a2 = fmaxf(fminf(a1, b1), fmaxf(a2, b2));
            a1 = fmaxf(a1, b1);
            ai = g ? bi : ai;
        }
        const int n = n0 + tid;
        ids[n] = ai;
        atomicAdd(&counts[ai], 1);
        if (a1 - a2 < 2.5e-3f) {
            int p = atomicAdd(flag_cnt, 1);
            flag_list[p] = n;
        }
    }
}

// batched numpy-fp32-path rescore: 16 rows/group x 8 k-slices per block.
#define RG 16
__global__ __launch_bounds__(256) void k_rescore(
    const float* __restrict__ x, const float* __restrict__ embedT,
    const float* __restrict__ e2np, const int* __restrict__ flag_cnt,
    const int* __restrict__ flag_list, float* __restrict__ pbd, int* __restrict__ pbi)
{
    __shared__ float rowl[RG][256];
    __shared__ float sq[RG][256];
    __shared__ float x2s[RG];
    __shared__ float bdA[256];
    __shared__ int   biA[256];
    const int tid = threadIdx.x;
    int cnt = *flag_cnt; if (cnt > 2048) cnt = 2048;
    const int ngroups = (cnt + RG - 1) / RG;
    const int kt = blockIdx.x & 7;
    for (int g = blockIdx.x >> 3; g < ngroups; g += 64) {
        #pragma unroll
        for (int i = 0; i < RG; ++i) {
            int f = g * RG + i;
            float v = 0.f;
            if (f < cnt) {
                int n = flag_list[f];
                int b = n >> 10, wq = (n >> 5) & 31, hq = n & 31;
                v = x[((size_t)(b * 256 + tid)) * 1024 + hq * 32 + wq];
            }
            rowl[i][tid] = v;
            sq[i][tid] = v * v;       // product rounds at LDS store
        }
        __syncthreads();
        if (tid < RG) x2s[tid] = np_pw128(sq[tid]) + np_pw128(sq[tid] + 128);
        __syncthreads();

        float acc[RG][4];
        #pragma unroll
        for (int r = 0; r < RG; ++r)
            #pragma unroll
            for (int e = 0; e < 4; ++e) acc[r][e] = 0.f;
        for (int c = 0; c < 256; ++c) {
            const f32x4 bv = *(const f32x4*)&embedT[(size_t)c * KD + kt * 1024 + tid * 4];
            #pragma unroll
            for (int r = 0; r < RG; ++r) {
                const float av = rowl[r][c];
                acc[r][0] = fmaf(av, bv[0], acc[r][0]);
                acc[r][1] = fmaf(av, bv[1], acc[r][1]);
                acc[r][2] = fmaf(av, bv[2], acc[r][2]);
                acc[r][3] = fmaf(av, bv[3], acc[r][3]);
            }
        }
        #pragma unroll
        for (int r = 0; r < RG; ++r) {
            float bd = 3.4e38f; int bi = 0x7fffffff;
            #pragma unroll
            for (int e = 0; e < 4; ++e) {
                const int k = kt * 1024 + tid * 4 + e;
                const float d2 = (x2s[r] - 2.0f * acc[r][e]) + e2np[k];
                if (d2 < bd || (d2 == bd && k < bi)) { bd = d2; bi = k; }
            }
            bdA[tid] = bd; biA[tid] = bi;
            __syncthreads();
            for (int off = 128; off > 0; off >>= 1) {
                if (tid < off) {
                    float od = bdA[tid + off]; int oi = biA[tid + off];
                    if (od < bdA[tid] || (od == bdA[tid] && oi < biA[tid])) {
                        bdA[tid] = od; biA[tid] = oi;
                    }
                }
                __syncthreads();
            }
            if (tid == 0) {
                int f = g * RG + r;
                if (f < cnt) { pbd[f * 8 + kt] = bdA[0]; pbi[f * 8 + kt] = biA[0]; }
            }
            __syncthreads();
        }
    }
}

// merge kt-slices; adjust ids + counts for changed rows
__global__ void k_flagmerge(const int* __restrict__ flag_cnt, const int* __restrict__ flag_list,
                            const float* __restrict__ pbd, const int* __restrict__ pbi,
                            int* __restrict__ ids, int* __restrict__ counts) {
    int cnt = *flag_cnt; if (cnt > 2048) cnt = 2048;
    int f = blockIdx.x * 256 + threadIdx.x;
    if (f >= cnt) return;
    float bd = pbd[f * 8]; int bi = pbi[f * 8];
    #pragma unroll
    for (int kt = 1; kt < 8; ++kt) {
        float d = pbd[f * 8 + kt]; int i = pbi[f * 8 + kt];
        if (d < bd || (d == bd && i < bi)) { bd = d; bi = i; }
    }
    const int n = flag_list[f];
    const int old = ids[n];
    if (bi != old) {
        ids[n] = bi;
        atomicAdd(&counts[old], -1);
        atomicAdd(&counts[bi], 1);
    }
}

// st_out (= vqs) + loss, coalesced + float4-vectorized via LDS transpose.
__global__ __launch_bounds__(256) void k_output(
    const float* __restrict__ x, const float* __restrict__ embed,
    const int* __restrict__ ids, float* __restrict__ st,
    float* __restrict__ loss_ws)
{
    const int b = blockIdx.x >> 5, h = blockIdx.x & 31;
    const int tid = threadIdx.x;
    __shared__ int sid[32];
    __shared__ float vq[256 * 33];
    if (tid < 32) sid[tid] = ids[b * 1024 + tid * 32 + h];
    __syncthreads();
    #pragma unroll 4
    for (int w = 0; w < 32; ++w) {
        vq[tid * 33 + w] = embed[(size_t)sid[w] * CD + tid];
    }
    __syncthreads();
    float lsum = 0.f;
    const int j4 = (tid & 7) * 4;
    const int c0 = tid >> 3;
    const size_t base0 = (((size_t)b * 256) * 32 + h) * 32;
    #pragma unroll
    for (int it = 0; it < 8; ++it) {
        const int c = it * 32 + c0;
        const size_t a = base0 + (size_t)c * 1024 + j4;
        const float4 xv = *(const float4*)(x + a);
        float4 vv;
        vv.x = vq[c * 33 + j4 + 0];
        vv.y = vq[c * 33 + j4 + 1];
        vv.z = vq[c * 33 + j4 + 2];
        vv.w = vq[c * 33 + j4 + 3];
        *(float4*)(st + a) = vv;
        const float d0 = vv.x - xv.x, d1 = vv.y - xv.y;
        const float d2 = vv.z - xv.z, d3 = vv.w - xv.w;
        lsum = fmaf(d0, d0, lsum); lsum = fmaf(d1, d1, lsum);
        lsum = fmaf(d2, d2, lsum); lsum = fmaf(d3, d3, lsum);
    }
    #pragma unroll
    for (int off = 1; off < 64; off <<= 1) lsum += __shfl_xor(lsum, off);
    if ((tid & 63) == 0) atomicAdd(loss_ws, lsum);
}

__global__ void k_scan(const int* __restrict__ counts, int* __restrict__ offs,
                       float* __restrict__ track_num) {
    __shared__ int ps[257];
    const int tid = threadIdx.x;
    int loc[32]; int s = 0;
    const int base = tid * 32;
    #pragma unroll
    for (int j = 0; j < 32; ++j) { loc[j] = s; s += counts[base + j]; }
    ps[tid + 1] = s;
    if (tid == 0) ps[0] = 0;
    __syncthreads();
    if (tid == 0) for (int i = 1; i <= 256; ++i) ps[i] += ps[i - 1];
    __syncthreads();
    const int pre = ps[tid];
    #pragma unroll
    for (int j = 0; j < 32; ++j) {
        offs[base + j] = pre + loc[j];
        track_num[base + j] = (float)counts[base + j];
    }
}

// bucket fill + ids_out (fused)
__global__ void k_fill(const int* __restrict__ ids, const int* __restrict__ offs,
                       int* __restrict__ cursor, int* __restrict__ bucket,
                       float* __restrict__ ids_out) {
    int n = blockIdx.x * 256 + threadIdx.x;
    int id = ids[n];
    int p = atomicAdd(&cursor[id], 1);
    bucket[offs[id] + p] = n;
    int b = n >> 10, w = (n >> 5) & 31, h = n & 31;
    ids_out[b * 1024 + h * 32 + w] = (float)id;
}

// track_enc + new_embed + loss_out (after k_output in stream)
__global__ void k_gather(const _Float16* __restrict__ xh, const _Float16* __restrict__ xl,
                         const int* __restrict__ offs, const int* __restrict__ counts,
                         const int* __restrict__ bucket, float* __restrict__ enc,
                         float* __restrict__ nemb, const float* __restrict__ loss_ws,
                         float* __restrict__ loss_out) {
    const int k = blockIdx.x, c = threadIdx.x;
    const int o = offs[k], cnt = counts[k];
    float s = 0.f;
    for (int i = 0; i < cnt; ++i) {
        int n = bucket[o + i];
        s += (float)xh[(size_t)n * CD + c] + (float)xl[(size_t)n * CD + c];
    }
    enc[(size_t)k * CD + c] = s;
    const float factor = 1.0f + (1e-5f * 8192.0f) / 32768.0f;
    nemb[(size_t)k * CD + c] = s * factor / ((float)cnt + 1e-5f);
    if (k == 0 && c == 0) loss_out[0] = loss_ws[0] * (1.0f / 8388608.0f);
}

extern "C" void kernel_launch(void* const* d_in, const int* in_sizes, int n_in,
                              void* d_out, int out_size, void* d_ws, size_t ws_size,
                              hipStream_t stream)
{
    const float* x     = (const float*)d_in[0];
    const float* embed = (const float*)d_in[1];
    float* out = (float*)d_out;
    float* ws  = (float*)d_ws;

    _Float16* xh = (_Float16*)(ws + F_XH);
    _Float16* xl = (_Float16*)(ws + F_XL);
    _Float16* eh = (_Float16*)(ws + F_EH);
    float* embedT    = ws + F_EMBT;
    float* e2n       = ws + F_E2N;
    float* e2np      = ws + F_E2NP;
    int*   ids       = (int*)(ws + F_IDS);
    int*   flag_cnt  = (int*)(ws + F_FLAGCNT);
    float* loss_ws   = ws + F_LOSS;
    int*   flag_list = (int*)(ws + F_FLAGLST);
    int*   counts    = (int*)(ws + F_COUNTS);
    int*   cursor    = (int*)(ws + F_CURSOR);
    int*   offs      = (int*)(ws + F_OFFS);
    int*   bucket    = (int*)(ws + F_BUCKET);
    float* pbd       = ws + F_PBD;
    int*   pbi       = (int*)(ws + F_PBI);

    hipMemsetAsync(ws + F_FLAGCNT, 0, 2 * sizeof(float), stream);          // flag_cnt + loss
    hipMemsetAsync(ws + F_COUNTS, 0, 2 * 8192 * sizeof(float), stream);    // counts + cursor

    k_cvt_x    <<<512,  256, 0, stream>>>(x, xh, xl);
    k_prep_e2  <<<256,  256, 0, stream>>>(embed, eh, e2n, e2np);
    k_epose    <<<512,  256, 0, stream>>>(embed, embedT);
    k_mfma     <<<256,  512, 0, stream>>>(xh, eh, e2n, ids, flag_cnt, flag_list, counts);
    k_rescore  <<<512,  256, 0, stream>>>(x, embedT, e2np, flag_cnt, flag_list, pbd, pbi);
    k_flagmerge<<<8,    256, 0, stream>>>(flag_cnt, flag_list, pbd, pbi, ids, counts);
    k_output   <<<1024, 256, 0, stream>>>(x, embed, ids, out + OUT_ST, loss_ws);
    k_scan     <<<1,    256, 0, stream>>>(counts, offs, out + OUT_NUM);
    k_fill     <<<128,  256, 0, stream>>>(ids, offs, cursor, bucket, out + OUT_IDS);
    k_gather   <<<8192, 256, 0, stream>>>(xh, xl, offs, counts, bucket, out + OUT_ENC,
                                          out + OUT_NEMB, loss_ws, out + OUT_LOSS);
}

// Round 16
// 357.726 us; speedup vs baseline: 1.1035x; 1.0905x over previous
//
#include <hip/hip_runtime.h>

#define NR 32768   // rows (b*w*h)
#define CD 256     // emb dim
#define KD 8192    // dict size

typedef __attribute__((ext_vector_type(8))) _Float16 f16x8;
typedef __attribute__((ext_vector_type(4))) _Float16 f16x4;
typedef __attribute__((ext_vector_type(4))) float f32x4;

// ---- workspace float offsets ----
#define F_XH      0ull          // f16[32768][256] hi  (16MB)
#define F_XL      4194304ull    // f16[32768][256] lo  (16MB)
#define F_EH      8388608ull    // f16[8192][256] hi   (4MB)
#define F_EMBT    9437184ull    // fp32 embedT[256][8192] (8MB, rescore)
#define F_E2N     11534336ull   // 8192  (-0.5*e2, fast path)
#define F_E2NP    11542528ull   // 8192  (numpy-emulated e2)
#define F_IDS     11550720ull   // 32768 ints
#define F_FLAGCNT 11583488ull
#define F_LOSS    11583489ull
#define F_FLAGLST 11583490ull   // up to 32768 ints
#define F_COUNTS  11616258ull   // 8192 ints
#define F_CURSOR  11624450ull   // 8192 ints
#define F_OFFS    11632642ull   // 8192 ints
#define F_BUCKET  11640834ull   // 32768 ints
#define F_PBD     11673602ull   // 2048*8 floats
#define F_PBI     11689986ull   // 2048*8 ints

// ---- output float offsets ----
#define OUT_ST   0ull
#define OUT_LOSS 8388608ull
#define OUT_IDS  8388609ull
#define OUT_NEMB 8421377ull
#define OUT_NUM  10518529ull
#define OUT_ENC  10526721ull

// numpy pairwise_sum for a 128-block: 8 accumulators, fixed combine tree.
__device__ __forceinline__ float np_pw128(const float* p) {
    float r0 = p[0], r1 = p[1], r2 = p[2], r3 = p[3];
    float r4 = p[4], r5 = p[5], r6 = p[6], r7 = p[7];
    for (int i = 8; i < 128; i += 8) {
        r0 += p[i + 0]; r1 += p[i + 1]; r2 += p[i + 2]; r3 += p[i + 3];
        r4 += p[i + 4]; r5 += p[i + 5]; r6 += p[i + 6]; r7 += p[i + 7];
    }
    return ((r0 + r1) + (r2 + r3)) + ((r4 + r5) + (r6 + r7));
}

// x (b,c,h,w) -> xh/xl[n][c] f16 split, n = b*1024 + w*32 + h
__global__ void k_cvt_x(const float* __restrict__ x,
                        _Float16* __restrict__ xh, _Float16* __restrict__ xl) {
    __shared__ float t[32 * 529];   // [c32][h16*33 + w]
    const int bx = blockIdx.x;
    const int b = bx >> 4, cg = (bx >> 1) & 7, h0 = (bx & 1) * 16;
    const int tid = threadIdx.x;
    const float* src = x + ((size_t)(b * 256 + cg * 32)) * 1024 + h0 * 32;
    #pragma unroll 4
    for (int i = 0; i < 16; ++i) {
        const int e4 = i * 256 + tid;          // quad index
        const int c = e4 >> 7, rem = e4 & 127;
        const int hh = rem >> 3, w4 = (rem & 7) * 4;
        const float4 v = *(const float4*)(src + (size_t)c * 1024 + hh * 32 + w4);
        float* dst = &t[c * 529 + hh * 33 + w4];
        dst[0] = v.x; dst[1] = v.y; dst[2] = v.z; dst[3] = v.w;
    }
    __syncthreads();
    const int nj = tid >> 3;              // 32 rows per iter
    const int c4 = (tid & 7) * 4;         // 4 consecutive c per lane
    #pragma unroll 4
    for (int i = 0; i < 16; ++i) {
        const int ns = i * 32 + nj;       // 0..511 = w*16 + hh
        const int w = ns >> 4, hh = ns & 15;
        f16x4 hv, lv;
        #pragma unroll
        for (int j = 0; j < 4; ++j) {
            const float v = t[(c4 + j) * 529 + hh * 33 + w];
            const _Float16 hi = (_Float16)v;
            hv[j] = hi;
            lv[j] = (_Float16)(v - (float)hi);
        }
        const size_t o = ((size_t)(b * 1024 + w * 32 + h0 + hh)) * 256 + cg * 32 + c4;
        *(f16x4*)&xh[o] = hv;
        *(f16x4*)&xl[o] = lv;
    }
}

// fused embed prep: eh f16 + e2n = -0.5*|e|^2 + numpy-emulated e2np.
__global__ void k_prep_e2(const float* __restrict__ embed, _Float16* __restrict__ eh,
                          float* __restrict__ e2n, float* __restrict__ e2np) {
    const int lane = threadIdx.x & 63;
    const int wv = threadIdx.x >> 6;
    #pragma unroll
    for (int i = 0; i < 8; ++i) {
        const int k = blockIdx.x * 32 + wv * 8 + i;
        const float4 v = *(const float4*)(embed + (size_t)k * CD + lane * 4);
        f16x4 h;
        h[0] = (_Float16)v.x; h[1] = (_Float16)v.y;
        h[2] = (_Float16)v.z; h[3] = (_Float16)v.w;
        *(f16x4*)&eh[(size_t)k * CD + lane * 4] = h;
        float s = v.x * v.x + v.y * v.y + v.z * v.z + v.w * v.w;
        #pragma unroll
        for (int off = 1; off < 64; off <<= 1) s += __shfl_xor(s, off);
        if (lane == 0) e2n[k] = -0.5f * s;
    }
    const int k = blockIdx.x * 32 + wv * 8 + (lane >> 3);
    const int j = lane & 7;
    float hsum[2];
    #pragma unroll
    for (int half = 0; half < 2; ++half) {
        float r = 0.f;
        for (int i = 0; i < 16; ++i) {
            float v = embed[(size_t)k * CD + half * 128 + j + i * 8];
            float sq = v * v;
            asm volatile("" : "+v"(sq));   // round v*v to fp32 (block contraction)
            r += sq;
        }
        float s = r + __shfl_xor(r, 1);
        s = s + __shfl_xor(s, 2);
        s = s + __shfl_xor(s, 4);
        hsum[half] = s;
    }
    if (j == 0) e2np[k] = hsum[0] + hsum[1];
}

// embed (k,c) -> embedT[c][k] fp32 (rescore only)
__global__ void k_epose(const float* __restrict__ embed, float* __restrict__ embedT) {
    int kt = blockIdx.x >> 2, ct = blockIdx.x & 3;
    __shared__ float t[64][65];
    int tid = threadIdx.x;
    #pragma unroll
    for (int i = 0; i < 16; ++i) {
        int e = tid + i * 256; int r = e >> 6, c = e & 63;
        t[r][c] = embed[(size_t)(kt * 64 + r) * CD + ct * 64 + c];
    }
    __syncthreads();
    #pragma unroll
    for (int i = 0; i < 16; ++i) {
        int e = tid + i * 256; int c = e >> 6, r = e & 63;
        embedT[(size_t)(ct * 64 + c) * KD + kt * 64 + r] = t[r][c];
    }
}

// ============================================================================
// Operand-swapped MFMA argmin — R11-proven lockstep pipeline (170.5us) plus
// fb REGISTER CACHE: B is immutable after the prologue, and each wave re-reads
// the same 4x8 fb fragment set every window. Cache cc=0..3 in fbreg[4][4]
// (64 VGPRs, static indices) -> B LDS reads halve; steps cc<4 issue no
// fb ds_read. Everything else byte-identical to R11.
// ============================================================================
#define LDSB 0
#define LDSA 65536
#define LDSM 131072
__global__ __launch_bounds__(512, 1) void k_mfma(
    const _Float16* __restrict__ xh, const _Float16* __restrict__ eh,
    const float* __restrict__ e2n, int* __restrict__ ids,
    int* __restrict__ flag_cnt, int* __restrict__ flag_list,
    int* __restrict__ counts)
{
    __shared__ char smem[131072 + 6144];   // B 64KB | A 4x16KB | merge/dummy 6KB
    const int tid = threadIdx.x;
    const int w = tid >> 6, l = tid & 63;
    const int wm = w & 3, wn = w >> 2;        // 4 code-waves x 2 row-waves
    const int lr = l & 15, q = l >> 4;
    const int n0 = blockIdx.x * 128;

    // ---- stage B (xh rows) resident, swizzled slot' = slot ^ (row&15) ----
    #pragma unroll
    for (int i = 0; i < 8; ++i) {
        const int row = i * 16 + (tid >> 5);
        const int slot = tid & 31;
        const _Float16* src = xh + (size_t)(n0 + row) * 256 + ((slot ^ (row & 15)) * 8);
        __builtin_amdgcn_global_load_lds(
            (const __attribute__((address_space(1))) unsigned int*)src,
            (__attribute__((address_space(3))) unsigned int*)(smem + LDSB + row * 512 + slot * 16),
            16, 0, 0);
    }

    // ---- A stage: step s covers codes [(s>>3)*256, +256) x c [(s&7)*32, +32).
    auto STAGE_A = [&](int s, int bufc) {
        if (s < 256) {
            const int bufo = LDSA + bufc * 16384;
            #pragma unroll
            for (int i = 0; i < 2; ++i) {
                const int code = i * 128 + (tid >> 2);
                const int slot = tid & 3;
                const _Float16* src = eh + (size_t)((s >> 3) * 256 + code) * 256
                                         + (s & 7) * 32 + ((slot ^ ((code >> 1) & 3)) * 8);
                __builtin_amdgcn_global_load_lds(
                    (const __attribute__((address_space(1))) unsigned int*)src,
                    (__attribute__((address_space(3))) unsigned int*)
                        (smem + bufo + code * 64 + slot * 16),
                    16, 0, 0);
            }
        } else {
            #pragma unroll
            for (int i = 0; i < 2; ++i) {
                __builtin_amdgcn_global_load_lds(
                    (const __attribute__((address_space(1))) unsigned int*)(eh + tid * 8),
                    (__attribute__((address_space(3))) unsigned int*)
                        (smem + LDSM + i * 1024 + (tid & 63) * 16),
                    16, 0, 0);
            }
        }
    };

    // ---- prologue: e2 bias for window 0, stage steps 0..2, wait step0 ----
    f32x4 e2c[4];
    #pragma unroll
    for (int m = 0; m < 4; ++m)
        e2c[m] = *(const f32x4*)(e2n + wm * 64 + m * 16 + q * 4);
    STAGE_A(0, 0); STAGE_A(1, 1); STAGE_A(2, 2);
    __builtin_amdgcn_sched_barrier(0);
    asm volatile("s_waitcnt vmcnt(4)" ::: "memory");
    __builtin_amdgcn_s_barrier();
    __builtin_amdgcn_sched_barrier(0);

    f32x4 acc[4][4];
    float m1[4], m2[4]; int i1[4];
    #pragma unroll
    for (int n = 0; n < 4; ++n) { m1[n] = -3.4e38f; m2[n] = -3.4e38f; i1[n] = 0; }

    // precomputed LDS offsets
    int faoff[4];
    #pragma unroll
    for (int m = 0; m < 4; ++m) {
        const int code = wm * 64 + m * 16 + lr;
        faoff[m] = code * 64 + ((q ^ ((code >> 1) & 3)) * 16);
    }
    int fboff[4], rx[4];
    #pragma unroll
    for (int n = 0; n < 4; ++n) {
        const int row = wn * 64 + n * 16 + lr;
        fboff[n] = LDSB + row * 512;
        rx[n] = row & 15;
    }

    // ---- fb register cache for cc = 0..3 (B immutable after prologue) ----
    f16x8 fbreg[4][4];
    #pragma unroll
    for (int n = 0; n < 4; ++n)
        #pragma unroll
        for (int cc = 0; cc < 4; ++cc)
            fbreg[n][cc] = *(const f16x8*)(smem + fboff[n] + (((cc * 4 + q) ^ rx[n]) * 16));

    #pragma unroll 1
    for (int cg = 0; cg < 32; ++cg) {
        #pragma unroll
        for (int cc = 0; cc < 8; ++cc) {
            const int s = cg * 8 + cc;
            if (cc == 6 && cg < 31) {   // prefetch next window's e2 bias
                #pragma unroll
                for (int m = 0; m < 4; ++m)
                    e2c[m] = *(const f32x4*)(e2n + (cg + 1) * 256 + wm * 64 + m * 16 + q * 4);
            }
            STAGE_A(s + 3, (cc + 3) & 3);
            const int bufo = LDSA + (cc & 3) * 16384;
            f16x8 fa[4], fb[4];
            #pragma unroll
            for (int m = 0; m < 4; ++m)
                fa[m] = *(const f16x8*)(smem + bufo + faoff[m]);
            #pragma unroll
            for (int n = 0; n < 4; ++n) {
                if (cc < 4) {
                    fb[n] = fbreg[n][cc];    // static index (unrolled cc)
                } else {
                    const int g = cc * 4 + q;
                    fb[n] = *(const f16x8*)(smem + fboff[n] + ((g ^ rx[n]) * 16));
                }
            }
            if (cc == 0) {
                #pragma unroll
                for (int m = 0; m < 4; ++m)
                    #pragma unroll
                    for (int n = 0; n < 4; ++n)
                        acc[m][n] = __builtin_amdgcn_mfma_f32_16x16x32_f16(fa[m], fb[n], e2c[m], 0, 0, 0);
            } else {
                #pragma unroll
                for (int m = 0; m < 4; ++m)
                    #pragma unroll
                    for (int n = 0; n < 4; ++n)
                        acc[m][n] = __builtin_amdgcn_mfma_f32_16x16x32_f16(fa[m], fb[n], acc[m][n], 0, 0, 0);
            }
            if (cc == 7) {   // fold window into per-lane top-2
                const int kb = cg * 256 + wm * 64 + q * 4;
                #pragma unroll
                for (int n = 0; n < 4; ++n)
                    #pragma unroll
                    for (int m = 0; m < 4; ++m)
                        #pragma unroll
                        for (int r = 0; r < 4; ++r) {
                            const float v = acc[m][n][r];
                            const bool g = v > m1[n];
                            m2[n] = fmaxf(m2[n], fminf(v, m1[n]));
                            m1[n] = fmaxf(m1[n], v);
                            i1[n] = g ? (kb + m * 16 + r) : i1[n];
                        }
            }
            __builtin_amdgcn_sched_barrier(0);
            asm volatile("s_waitcnt vmcnt(4)" ::: "memory");
            __builtin_amdgcn_s_barrier();
            __builtin_amdgcn_sched_barrier(0);
        }
    }

    // ---- cross-lane merge: lanes l, l+16, l+32, l+48 hold same row, diff codes
    #pragma unroll
    for (int off = 16; off < 64; off <<= 1) {
        #pragma unroll
        for (int n = 0; n < 4; ++n) {
            const float om1 = __shfl_xor(m1[n], off);
            const float om2 = __shfl_xor(m2[n], off);
            const int   oi  = __shfl_xor(i1[n], off);
            const bool g = om1 > m1[n];
            m2[n] = fmaxf(fminf(m1[n], om1), fmaxf(m2[n], om2));
            m1[n] = fmaxf(m1[n], om1);
            i1[n] = g ? oi : i1[n];
        }
    }
    // ---- cross-wave merge over wm (4 code-wave groups) via LDS ----
    float* sm1 = (float*)(smem + LDSM);
    float* sm2 = (float*)(smem + LDSM + 2048);
    int*   si1 = (int*)  (smem + LDSM + 4096);
    __syncthreads();    // full drain (incl. dummy loads into LDSM)
    if (q == 0) {
        #pragma unroll
        for (int n = 0; n < 4; ++n) {
            const int row = wn * 64 + n * 16 + lr;
            sm1[wm * 128 + row] = m1[n];
            sm2[wm * 128 + row] = m2[n];
            si1[wm * 128 + row] = i1[n];
        }
    }
    __syncthreads();
    if (tid < 128) {
        float a1 = sm1[tid], a2 = sm2[tid]; int ai = si1[tid];
        #pragma unroll
        for (int wq = 1; wq < 4; ++wq) {
            const float b1 = sm1[wq * 128 + tid], b2 = sm2[wq * 128 + tid];
            const int bi = si1[wq * 128 + tid];
            const bool g = b1 > a1;
            a2 = fmaxf(fminf(a1, b1), fmaxf(a2, b2));
            a1 = fmaxf(a1, b1);
            ai = g ? bi : ai;
        }
        const int n = n0 + tid;
        ids[n] = ai;
        atomicAdd(&counts[ai], 1);
        if (a1 - a2 < 2.5e-3f) {
            int p = atomicAdd(flag_cnt, 1);
            flag_list[p] = n;
        }
    }
}

// batched numpy-fp32-path rescore: 16 rows/group x 8 k-slices per block.
#define RG 16
__global__ __launch_bounds__(256) void k_rescore(
    const float* __restrict__ x, const float* __restrict__ embedT,
    const float* __restrict__ e2np, const int* __restrict__ flag_cnt,
    const int* __restrict__ flag_list, float* __restrict__ pbd, int* __restrict__ pbi)
{
    __shared__ float rowl[RG][256];
    __shared__ float sq[RG][256];
    __shared__ float x2s[RG];
    __shared__ float bdA[256];
    __shared__ int   biA[256];
    const int tid = threadIdx.x;
    int cnt = *flag_cnt; if (cnt > 2048) cnt = 2048;
    const int ngroups = (cnt + RG - 1) / RG;
    const int kt = blockIdx.x & 7;
    for (int g = blockIdx.x >> 3; g < ngroups; g += 64) {
        #pragma unroll
        for (int i = 0; i < RG; ++i) {
            int f = g * RG + i;
            float v = 0.f;
            if (f < cnt) {
                int n = flag_list[f];
                int b = n >> 10, wq = (n >> 5) & 31, hq = n & 31;
                v = x[((size_t)(b * 256 + tid)) * 1024 + hq * 32 + wq];
            }
            rowl[i][tid] = v;
            sq[i][tid] = v * v;       // product rounds at LDS store
        }
        __syncthreads();
        if (tid < RG) x2s[tid] = np_pw128(sq[tid]) + np_pw128(sq[tid] + 128);
        __syncthreads();

        float acc[RG][4];
        #pragma unroll
        for (int r = 0; r < RG; ++r)
            #pragma unroll
            for (int e = 0; e < 4; ++e) acc[r][e] = 0.f;
        for (int c = 0; c < 256; ++c) {
            const f32x4 bv = *(const f32x4*)&embedT[(size_t)c * KD + kt * 1024 + tid * 4];
            #pragma unroll
            for (int r = 0; r < RG; ++r) {
                const float av = rowl[r][c];
                acc[r][0] = fmaf(av, bv[0], acc[r][0]);
                acc[r][1] = fmaf(av, bv[1], acc[r][1]);
                acc[r][2] = fmaf(av, bv[2], acc[r][2]);
                acc[r][3] = fmaf(av, bv[3], acc[r][3]);
            }
        }
        #pragma unroll
        for (int r = 0; r < RG; ++r) {
            float bd = 3.4e38f; int bi = 0x7fffffff;
            #pragma unroll
            for (int e = 0; e < 4; ++e) {
                const int k = kt * 1024 + tid * 4 + e;
                const float d2 = (x2s[r] - 2.0f * acc[r][e]) + e2np[k];
                if (d2 < bd || (d2 == bd && k < bi)) { bd = d2; bi = k; }
            }
            bdA[tid] = bd; biA[tid] = bi;
            __syncthreads();
            for (int off = 128; off > 0; off >>= 1) {
                if (tid < off) {
                    float od = bdA[tid + off]; int oi = biA[tid + off];
                    if (od < bdA[tid] || (od == bdA[tid] && oi < biA[tid])) {
                        bdA[tid] = od; biA[tid] = oi;
                    }
                }
                __syncthreads();
            }
            if (tid == 0) {
                int f = g * RG + r;
                if (f < cnt) { pbd[f * 8 + kt] = bdA[0]; pbi[f * 8 + kt] = biA[0]; }
            }
            __syncthreads();
        }
    }
}

// merge kt-slices; adjust ids + counts for changed rows
__global__ void k_flagmerge(const int* __restrict__ flag_cnt, const int* __restrict__ flag_list,
                            const float* __restrict__ pbd, const int* __restrict__ pbi,
                            int* __restrict__ ids, int* __restrict__ counts) {
    int cnt = *flag_cnt; if (cnt > 2048) cnt = 2048;
    int f = blockIdx.x * 256 + threadIdx.x;
    if (f >= cnt) return;
    float bd = pbd[f * 8]; int bi = pbi[f * 8];
    #pragma unroll
    for (int kt = 1; kt < 8; ++kt) {
        float d = pbd[f * 8 + kt]; int i = pbi[f * 8 + kt];
        if (d < bd || (d == bd && i < bi)) { bd = d; bi = i; }
    }
    const int n = flag_list[f];
    const int old = ids[n];
    if (bi != old) {
        ids[n] = bi;
        atomicAdd(&counts[old], -1);
        atomicAdd(&counts[bi], 1);
    }
}

// st_out (= vqs) + loss, coalesced + float4-vectorized via LDS transpose.
__global__ __launch_bounds__(256) void k_output(
    const float* __restrict__ x, const float* __restrict__ embed,
    const int* __restrict__ ids, float* __restrict__ st,
    float* __restrict__ loss_ws)
{
    const int b = blockIdx.x >> 5, h = blockIdx.x & 31;
    const int tid = threadIdx.x;
    __shared__ int sid[32];
    __shared__ float vq[256 * 33];
    if (tid < 32) sid[tid] = ids[b * 1024 + tid * 32 + h];
    __syncthreads();
    #pragma unroll 4
    for (int w = 0; w < 32; ++w) {
        vq[tid * 33 + w] = embed[(size_t)sid[w] * CD + tid];
    }
    __syncthreads();
    float lsum = 0.f;
    const int j4 = (tid & 7) * 4;
    const int c0 = tid >> 3;
    const size_t base0 = (((size_t)b * 256) * 32 + h) * 32;
    #pragma unroll
    for (int it = 0; it < 8; ++it) {
        const int c = it * 32 + c0;
        const size_t a = base0 + (size_t)c * 1024 + j4;
        const float4 xv = *(const float4*)(x + a);
        float4 vv;
        vv.x = vq[c * 33 + j4 + 0];
        vv.y = vq[c * 33 + j4 + 1];
        vv.z = vq[c * 33 + j4 + 2];
        vv.w = vq[c * 33 + j4 + 3];
        *(float4*)(st + a) = vv;
        const float d0 = vv.x - xv.x, d1 = vv.y - xv.y;
        const float d2 = vv.z - xv.z, d3 = vv.w - xv.w;
        lsum = fmaf(d0, d0, lsum); lsum = fmaf(d1, d1, lsum);
        lsum = fmaf(d2, d2, lsum); lsum = fmaf(d3, d3, lsum);
    }
    #pragma unroll
    for (int off = 1; off < 64; off <<= 1) lsum += __shfl_xor(lsum, off);
    if ((tid & 63) == 0) atomicAdd(loss_ws, lsum);
}

__global__ void k_scan(const int* __restrict__ counts, int* __restrict__ offs,
                       float* __restrict__ track_num) {
    __shared__ int ps[257];
    const int tid = threadIdx.x;
    int loc[32]; int s = 0;
    const int base = tid * 32;
    #pragma unroll
    for (int j = 0; j < 32; ++j) { loc[j] = s; s += counts[base + j]; }
    ps[tid + 1] = s;
    if (tid == 0) ps[0] = 0;
    __syncthreads();
    if (tid == 0) for (int i = 1; i <= 256; ++i) ps[i] += ps[i - 1];
    __syncthreads();
    const int pre = ps[tid];
    #pragma unroll
    for (int j = 0; j < 32; ++j) {
        offs[base + j] = pre + loc[j];
        track_num[base + j] = (float)counts[base + j];
    }
}

// bucket fill + ids_out (fused)
__global__ void k_fill(const int* __restrict__ ids, const int* __restrict__ offs,
                       int* __restrict__ cursor, int* __restrict__ bucket,
                       float* __restrict__ ids_out) {
    int n = blockIdx.x * 256 + threadIdx.x;
    int id = ids[n];
    int p = atomicAdd(&cursor[id], 1);
    bucket[offs[id] + p] = n;
    int b = n >> 10, w = (n >> 5) & 31, h = n & 31;
    ids_out[b * 1024 + h * 32 + w] = (float)id;
}

// track_enc + new_embed + loss_out (after k_output in stream)
__global__ void k_gather(const _Float16* __restrict__ xh, const _Float16* __restrict__ xl,
                         const int* __restrict__ offs, const int* __restrict__ counts,
                         const int* __restrict__ bucket, float* __restrict__ enc,
                         float* __restrict__ nemb, const float* __restrict__ loss_ws,
                         float* __restrict__ loss_out) {
    const int k = blockIdx.x, c = threadIdx.x;
    const int o = offs[k], cnt = counts[k];
    float s = 0.f;
    for (int i = 0; i < cnt; ++i) {
        int n = bucket[o + i];
        s += (float)xh[(size_t)n * CD + c] + (float)xl[(size_t)n * CD + c];
    }
    enc[(size_t)k * CD + c] = s;
    const float factor = 1.0f + (1e-5f * 8192.0f) / 32768.0f;
    nemb[(size_t)k * CD + c] = s * factor / ((float)cnt + 1e-5f);
    if (k == 0 && c == 0) loss_out[0] = loss_ws[0] * (1.0f / 8388608.0f);
}

extern "C" void kernel_launch(void* const* d_in, const int* in_sizes, int n_in,
                              void* d_out, int out_size, void* d_ws, size_t ws_size,
                              hipStream_t stream)
{
    const float* x     = (const float*)d_in[0];
    const float* embed = (const float*)d_in[1];
    float* out = (float*)d_out;
    float* ws  = (float*)d_ws;

    _Float16* xh = (_Float16*)(ws + F_XH);
    _Float16* xl = (_Float16*)(ws + F_XL);
    _Float16* eh = (_Float16*)(ws + F_EH);
    float* embedT    = ws + F_EMBT;
    float* e2n       = ws + F_E2N;
    float* e2np      = ws + F_E2NP;
    int*   ids       = (int*)(ws + F_IDS);
    int*   flag_cnt  = (int*)(ws + F_FLAGCNT);
    float* loss_ws   = ws + F_LOSS;
    int*   flag_list = (int*)(ws + F_FLAGLST);
    int*   counts    = (int*)(ws + F_COUNTS);
    int*   cursor    = (int*)(ws + F_CURSOR);
    int*   offs      = (int*)(ws + F_OFFS);
    int*   bucket    = (int*)(ws + F_BUCKET);
    float* pbd       = ws + F_PBD;
    int*   pbi       = (int*)(ws + F_PBI);

    hipMemsetAsync(ws + F_FLAGCNT, 0, 2 * sizeof(float), stream);          // flag_cnt + loss
    hipMemsetAsync(ws + F_COUNTS, 0, 2 * 8192 * sizeof(float), stream);    // counts + cursor

    k_cvt_x    <<<512,  256, 0, stream>>>(x, xh, xl);
    k_prep_e2  <<<256,  256, 0, stream>>>(embed, eh, e2n, e2np);
    k_epose    <<<512,  256, 0, stream>>>(embed, embedT);
    k_mfma     <<<256,  512, 0, stream>>>(xh, eh, e2n, ids, flag_cnt, flag_list, counts);
    k_rescore  <<<512,  256, 0, stream>>>(x, embedT, e2np, flag_cnt, flag_list, pbd, pbi);
    k_flagmerge<<<8,    256, 0, stream>>>(flag_cnt, flag_list, pbd, pbi, ids, counts);
    k_output   <<<1024, 256, 0, stream>>>(x, embed, ids, out + OUT_ST, loss_ws);
    k_scan     <<<1,    256, 0, stream>>>(counts, offs, out + OUT_NUM);
    k_fill     <<<128,  256, 0, stream>>>(ids, offs, cursor, bucket, out + OUT_IDS);
    k_gather   <<<8192, 256, 0, stream>>>(xh, xl, offs, counts, bucket, out + OUT_ENC,
                                          out + OUT_NEMB, loss_ws, out + OUT_LOSS);
}